// Round 1
// 679.691 us; speedup vs baseline: 1.0130x; 1.0130x over previous
//
#include <hip/hip_runtime.h>
#include <hip/hip_bf16.h>

typedef __attribute__((ext_vector_type(8))) short short8;
typedef __attribute__((ext_vector_type(4))) float floatx4;

#define NB 64
#define NS 512
#define ND 768
#define NH 12

__device__ __forceinline__ float bf2f(unsigned short u) {
  union { unsigned int i; float f; } v; v.i = ((unsigned int)u) << 16; return v.f;
}
__device__ __forceinline__ unsigned short f2bf(float f) {
  union { float f; unsigned int i; } v; v.f = f;
  unsigned int i = v.i;
  unsigned int r = i + 0x7fffu + ((i >> 16) & 1u);
  return (unsigned short)(r >> 16);
}

// async global->LDS, 16B per lane. LDS dest is wave-uniform base + lane*16.
__device__ __forceinline__ void gload_lds16(const unsigned short* g, unsigned short* l) {
  __builtin_amdgcn_global_load_lds(
      (const __attribute__((address_space(1))) unsigned int*)g,
      (__attribute__((address_space(3))) unsigned int*)l, 16, 0, 0);
}

// ------- fp32 -> bf16 convert: 4 elements/thread -------
__global__ void convert_k(const float* __restrict__ src, unsigned short* __restrict__ dst,
                          int n4) {
  int i = blockIdx.x * 256 + threadIdx.x;
  if (i >= n4) return;
  float4 v = ((const float4*)src)[i];
  ushort4 o;
  o.x = f2bf(v.x); o.y = f2bf(v.y); o.z = f2bf(v.z); o.w = f2bf(v.w);
  ((ushort4*)dst)[i] = o;
}

// ------- transpose + convert: in (R x C fp32) -> out (C x R bf16) ----
__global__ void transpose_cvt_k(const float* __restrict__ in, unsigned short* __restrict__ out,
                                int R, int C) {
  __shared__ unsigned short tile[32][33];
  int c0 = blockIdx.x * 32, r0 = blockIdx.y * 32;
  int tx = threadIdx.x, ty = threadIdx.y;
#pragma unroll
  for (int i = 0; i < 32; i += 8)
    tile[ty + i][tx] = f2bf(in[(r0 + ty + i) * C + c0 + tx]);
  __syncthreads();
#pragma unroll
  for (int i = 0; i < 32; i += 8) out[(c0 + ty + i) * R + r0 + tx] = tile[tx][ty + i];
}

// ---------------- GEMM: C = A(MxK bf16) * Bt(NxK bf16)^T + bias(fp32) ----------------
// m97 structure: global_load_lds width-16 staging into linear [128][32] LDS tiles,
// 4 waves, 4x4 x (16x16x32) MFMA per wave, XCD-aware block swizzle.
// MODE 0: fp32 store to out[m*N+n].  MODE 1: bf16 scatter into Q/K (B,H,S,64), Vt (B,H,64,S).
template <int MODE>
__global__ __launch_bounds__(256) void gemm_k(
    const unsigned short* __restrict__ A, const unsigned short* __restrict__ Bt,
    const float* __restrict__ bias, float* __restrict__ out,
    unsigned short* __restrict__ Qg, unsigned short* __restrict__ Kg,
    unsigned short* __restrict__ Vtg, int M, int N, int K) {
  __shared__ unsigned short As[128 * 32];  // linear: global_load_lds needs contiguous dest
  __shared__ unsigned short Bs[128 * 32];

  // XCD-aware swizzle (nwg % 8 == 0 for both GEMMs: 4608, 1536)
  int nbx = N >> 7;
  int nwg = (M >> 7) * nbx;
  int id = blockIdx.x;
  int q8 = nwg >> 3;
  int wg = (id & 7) * q8 + (id >> 3);
  int bx = wg % nbx, by = wg / nbx;
  int n0 = bx * 128, m0 = by * 128;

  int t = threadIdx.x;
  int w = t >> 6, lane = t & 63;
  int wm = (w >> 1) * 64, wn = (w & 1) * 64;
  int lr = lane & 15, lq = lane >> 4;

  // staging: wave w instr0 covers rows w*16 + (lane>>2), cols (lane&3)*8
  int srow = w * 16 + (lane >> 2);
  int scol = (lane & 3) * 8;
  const unsigned short* Ag = A + (size_t)(m0 + srow) * K + scol;
  const unsigned short* Bg = Bt + (size_t)(n0 + srow) * K + scol;
  unsigned short* lA0 = &As[w * 512];
  unsigned short* lA1 = &As[2048 + w * 512];
  unsigned short* lB0 = &Bs[w * 512];
  unsigned short* lB1 = &Bs[2048 + w * 512];
  const size_t rowskip = (size_t)64 * K;

  floatx4 acc[4][4];
#pragma unroll
  for (int i = 0; i < 4; i++)
#pragma unroll
    for (int j = 0; j < 4; j++) acc[i][j] = (floatx4){0.f, 0.f, 0.f, 0.f};

  for (int k0 = 0; k0 < K; k0 += 32) {
    gload_lds16(Ag + k0, lA0);
    gload_lds16(Ag + rowskip + k0, lA1);
    gload_lds16(Bg + k0, lB0);
    gload_lds16(Bg + rowskip + k0, lB1);
    __syncthreads();  // compiler emits s_waitcnt vmcnt(0) before s_barrier
    short8 af[4], bfr[4];
#pragma unroll
    for (int mt = 0; mt < 4; mt++) af[mt] = *(const short8*)&As[(wm + mt * 16 + lr) * 32 + lq * 8];
#pragma unroll
    for (int nt = 0; nt < 4; nt++) bfr[nt] = *(const short8*)&Bs[(wn + nt * 16 + lr) * 32 + lq * 8];
#pragma unroll
    for (int mt = 0; mt < 4; mt++)
#pragma unroll
      for (int nt = 0; nt < 4; nt++)
        acc[mt][nt] = __builtin_amdgcn_mfma_f32_16x16x32_bf16(af[mt], bfr[nt], acc[mt][nt], 0, 0, 0);
    __syncthreads();  // all reads done before next stage overwrites
  }

#pragma unroll
  for (int mt = 0; mt < 4; mt++) {
#pragma unroll
    for (int nt = 0; nt < 4; nt++) {
      int n = n0 + wn + nt * 16 + lr;
      float bv = bias[n];
#pragma unroll
      for (int r = 0; r < 4; r++) {
        int m = m0 + wm + mt * 16 + lq * 4 + r;  // C/D: row=(lane>>4)*4+reg, col=lane&15
        float fo = acc[mt][nt][r] + bv;
        if (MODE == 0) {
          out[(size_t)m * N + n] = fo;  // fp32 output (reference output dtype = float32)
        } else {
          unsigned short o = f2bf(fo);
          int b = m >> 9, s = m & 511;
          int part = n / ND;
          int within = n - part * ND;
          int h = within >> 6, d = within & 63;
          int bh = b * NH + h;
          if (part == 0)      Qg[(bh * NS + s) * 64 + d] = o;
          else if (part == 1) Kg[(bh * NS + s) * 64 + d] = o;
          else                Vtg[(bh * 64 + d) * NS + s] = o;  // V stored transposed
        }
      }
    }
  }
}

// ---------------- RoPE in place on Q and K (concat variant) ----------------
__global__ __launch_bounds__(256) void rope_k(unsigned short* __restrict__ Qg,
                                              unsigned short* __restrict__ Kg) {
  const int NR = NB * NH * NS;
  int t = threadIdx.x;
  int row = blockIdx.x * 8 + (t >> 5);
  int d = t & 31;
  unsigned short* p = (row < NR) ? Qg : Kg;
  int r = (row < NR) ? row : row - NR;
  int s = r & (NS - 1);
  float x1 = bf2f(p[r * 64 + 2 * d]);
  float x2 = bf2f(p[r * 64 + 2 * d + 1]);
  float ang = (float)s * __expf(-(float)d * 0.28782313662425572f);
  float sv, cv;
  __sincosf(ang, &sv, &cv);
  __syncthreads();
  p[r * 64 + d]      = f2bf(x1 * cv - x2 * sv);
  p[r * 64 + d + 32] = f2bf(x1 * sv + x2 * cv);
}

// ---------------- flash attention: 1 WG = (b,h) x 64 q-rows ----------------
__global__ __launch_bounds__(256) void attn_k(
    const unsigned short* __restrict__ Qg, const unsigned short* __restrict__ Kg,
    const unsigned short* __restrict__ Vtg, unsigned short* __restrict__ ctx) {
  __shared__ unsigned short Ks[64 * 72];
  __shared__ unsigned short Vs[64 * 72];
  __shared__ unsigned short Ps[4][16 * 72];
  int qt = blockIdx.x, bh = blockIdx.y;
  int t = threadIdx.x, w = t >> 6, lane = t & 63;
  int lr = lane & 15, lq = lane >> 4;
  int q0 = qt * 64 + w * 16;
  const unsigned short* Qb = Qg + (bh * NS + q0) * 64;
  short8 qf0 = *(const short8*)&Qb[lr * 64 + lq * 8];
  short8 qf1 = *(const short8*)&Qb[lr * 64 + 32 + lq * 8];
  floatx4 o[4];
#pragma unroll
  for (int ft = 0; ft < 4; ft++) o[ft] = (floatx4){0.f, 0.f, 0.f, 0.f};
  float m_[4] = {-1e30f, -1e30f, -1e30f, -1e30f};
  float l_[4] = {0.f, 0.f, 0.f, 0.f};
  int srow = t >> 2, scc = t & 3;
  const unsigned short* Kb = Kg + bh * NS * 64;
  const unsigned short* Vb = Vtg + bh * 64 * NS;

  for (int kt = 0; kt < 8; kt++) {
    __syncthreads();
    *(short8*)&Ks[srow * 72 + scc * 8]      = *(const short8*)&Kb[(kt * 64 + srow) * 64 + scc * 8];
    *(short8*)&Ks[srow * 72 + 32 + scc * 8] = *(const short8*)&Kb[(kt * 64 + srow) * 64 + 32 + scc * 8];
    *(short8*)&Vs[srow * 72 + scc * 8]      = *(const short8*)&Vb[srow * NS + kt * 64 + scc * 8];
    *(short8*)&Vs[srow * 72 + 32 + scc * 8] = *(const short8*)&Vb[srow * NS + kt * 64 + 32 + scc * 8];
    __syncthreads();

    floatx4 sf[4];
#pragma unroll
    for (int nt = 0; nt < 4; nt++) sf[nt] = (floatx4){0.f, 0.f, 0.f, 0.f};
#pragma unroll
    for (int nt = 0; nt < 4; nt++) {
      short8 k0 = *(const short8*)&Ks[(nt * 16 + lr) * 72 + lq * 8];
      short8 k1 = *(const short8*)&Ks[(nt * 16 + lr) * 72 + 32 + lq * 8];
      sf[nt] = __builtin_amdgcn_mfma_f32_16x16x32_bf16(qf0, k0, sf[nt], 0, 0, 0);
      sf[nt] = __builtin_amdgcn_mfma_f32_16x16x32_bf16(qf1, k1, sf[nt], 0, 0, 0);
    }
    float alpha[4];
#pragma unroll
    for (int r = 0; r < 4; r++) {
      float v = fmaxf(fmaxf(sf[0][r], sf[1][r]), fmaxf(sf[2][r], sf[3][r])) * 0.125f;
      v = fmaxf(v, __shfl_xor(v, 1));
      v = fmaxf(v, __shfl_xor(v, 2));
      v = fmaxf(v, __shfl_xor(v, 4));
      v = fmaxf(v, __shfl_xor(v, 8));
      float mn = fmaxf(m_[r], v);
      alpha[r] = __expf(m_[r] - mn);
      m_[r] = mn;
    }
    float rsum[4] = {0.f, 0.f, 0.f, 0.f};
#pragma unroll
    for (int nt = 0; nt < 4; nt++)
#pragma unroll
      for (int r = 0; r < 4; r++) {
        float pv = __expf(sf[nt][r] * 0.125f - m_[r]);
        rsum[r] += pv;
        Ps[w][(lq * 4 + r) * 72 + nt * 16 + lr] = f2bf(pv);
      }
#pragma unroll
    for (int r = 0; r < 4; r++) {
      float v = rsum[r];
      v += __shfl_xor(v, 1);
      v += __shfl_xor(v, 2);
      v += __shfl_xor(v, 4);
      v += __shfl_xor(v, 8);
      l_[r] = l_[r] * alpha[r] + v;
    }
#pragma unroll
    for (int ft = 0; ft < 4; ft++)
#pragma unroll
      for (int r = 0; r < 4; r++) o[ft][r] *= alpha[r];
#pragma unroll
    for (int ks = 0; ks < 2; ks++) {
      short8 pf = *(const short8*)&Ps[w][lr * 72 + ks * 32 + lq * 8];
#pragma unroll
      for (int ft = 0; ft < 4; ft++) {
        short8 vf = *(const short8*)&Vs[(ft * 16 + lr) * 72 + ks * 32 + lq * 8];
        o[ft] = __builtin_amdgcn_mfma_f32_16x16x32_bf16(pf, vf, o[ft], 0, 0, 0);
      }
    }
  }
  int b = bh / NH, h = bh - (bh / NH) * NH;
#pragma unroll
  for (int r = 0; r < 4; r++) {
    float inv = 1.f / l_[r];
#pragma unroll
    for (int ft = 0; ft < 4; ft++)
      ctx[(b * NS + q0 + lq * 4 + r) * ND + h * 64 + ft * 16 + lr] = f2bf(o[ft][r] * inv);
  }
}

extern "C" void kernel_launch(void* const* d_in, const int* in_sizes, int n_in,
                              void* d_out, int out_size, void* d_ws, size_t ws_size,
                              hipStream_t stream) {
  const float* x     = (const float*)d_in[0];   // fp32 (confirmed: bf16 read -> NaN)
  const float* w_qkv = (const float*)d_in[1];   // (768, 2304) fp32
  const float* b_qkv = (const float*)d_in[2];
  const float* w_o   = (const float*)d_in[3];   // (768, 768) fp32
  const float* b_o   = (const float*)d_in[4];
  float* out = (float*)d_out;                   // fp32: reference output dtype

  char* ws = (char*)d_ws;
  unsigned short* xb    = (unsigned short*)(ws);              // x bf16; reused as ctx
  unsigned short* wqkvT = (unsigned short*)(ws + 50331648);   // 2304x768 bf16
  unsigned short* woT   = (unsigned short*)(ws + 53870592);   // 768x768 bf16
  unsigned short* Qg    = (unsigned short*)(ws + 55050240);   // (B,H,S,64) bf16
  unsigned short* Kg    = (unsigned short*)(ws + 105381888);
  unsigned short* Vtg   = (unsigned short*)(ws + 155713536);
  unsigned short* ctx   = xb;  // x dead after QKV GEMM

  transpose_cvt_k<<<dim3(2304 / 32, 768 / 32), dim3(32, 8), 0, stream>>>(w_qkv, wqkvT, 768, 2304);
  transpose_cvt_k<<<dim3(768 / 32, 768 / 32), dim3(32, 8), 0, stream>>>(w_o, woT, 768, 768);
  convert_k<<<24576, 256, 0, stream>>>(x, xb, 6291456);
  gemm_k<1><<<dim3((32768 / 128) * (2304 / 128)), dim3(256), 0, stream>>>(
      xb, wqkvT, b_qkv, nullptr, Qg, Kg, Vtg, 32768, 2304, 768);
  rope_k<<<dim3(2 * NB * NH * NS / 8), dim3(256), 0, stream>>>(Qg, Kg);
  attn_k<<<dim3(NS / 64, NB * NH), dim3(256), 0, stream>>>(Qg, Kg, Vtg, ctx);
  gemm_k<0><<<dim3((32768 / 128) * (768 / 128)), dim3(256), 0, stream>>>(
      ctx, woT, b_o, out, nullptr, nullptr, nullptr, 32768, 768, 768);
}